// Round 6
// baseline (226.532 us; speedup 1.0000x reference)
//
#include <hip/hip_runtime.h>
#include <hip/hip_bf16.h>

#define B_ 8
#define L_ 2048
#define D_ 256
#define BK 64
#define KSPLIT 4
#define KQ (L_/KSPLIT)         // 512 keys per split
#define NIT (KQ/BK)            // 8 iterations
#define NROW (B_*L_)           // 16384
#define NE ((size_t)B_*L_*D_)  // 4194304

typedef __attribute__((ext_vector_type(8))) _Float16 f16x8;
typedef __attribute__((ext_vector_type(4))) _Float16 hf4;
typedef __attribute__((ext_vector_type(4))) float f32x4;

#define MFMA16F(a,b,c) __builtin_amdgcn_mfma_f32_16x16x32_f16((a),(b),(c),0,0,0)
#define NEG_INF (-__builtin_inff())
#define MREF0 (-1.0e30f)
#define GLL(src,dst) __builtin_amdgcn_global_load_lds( \
    (const __attribute__((address_space(1))) void*)(src), \
    (__attribute__((address_space(3))) void*)(dst), 16, 0, 0)

__device__ __forceinline__ f32x4 fmax4(f32x4 a, f32x4 b){
  f32x4 r;
  r[0]=fmaxf(a[0],b[0]); r[1]=fmaxf(a[1],b[1]);
  r[2]=fmaxf(a[2],b[2]); r[3]=fmaxf(a[3],b[3]);
  return r;
}

// ---- prep: fp32 x -> fp16 x16 (row-major) + vtl (pre-tiled swizzled V^T) ----
// vtl tile kt (32 keys): [256 d][4 chunks][8 keys], phys chunk = kc ^ ((d>>1)&3)
__global__ void prep_k(const float* __restrict__ x,
                       _Float16* __restrict__ x16,
                       _Float16* __restrict__ vtl){
  __shared__ _Float16 T[64][258];      // [l][d], odd-ish stride for phase-2 reads
  const int t = threadIdx.x;
  const int l0 = blockIdx.x*64, b = blockIdx.y;
  const int r = t>>5, c = (t&31)*8;
  #pragma unroll
  for (int p=0;p<8;++p){
    int row = r + p*8;
    size_t idx = ((size_t)(b*L_ + l0 + row))*D_ + c;
    float4 v0 = *(const float4*)(x + idx);
    float4 v1 = *(const float4*)(x + idx + 4);
    f16x8 h;
    h[0]=(_Float16)v0.x; h[1]=(_Float16)v0.y; h[2]=(_Float16)v0.z; h[3]=(_Float16)v0.w;
    h[4]=(_Float16)v1.x; h[5]=(_Float16)v1.y; h[6]=(_Float16)v1.z; h[7]=(_Float16)v1.w;
    *(f16x8*)(x16 + idx) = h;
    #pragma unroll
    for (int j=0;j<8;++j) T[row][c+j] = h[j];
  }
  __syncthreads();
  _Float16* vb = vtl + ((size_t)(b*64 + blockIdx.x*2))*8192;
  #pragma unroll
  for (int i=0;i<8;++i){
    int n = t + 256*i;                 // chunk id over 2 tiles (0..2047)
    int q = n & 1023, tile = n>>10;
    int d = q>>2, ph = q&3;
    int kc = ph ^ ((d>>1)&3);
    int k0 = tile*32 + kc*8;
    f16x8 h;
    #pragma unroll
    for (int j=0;j<8;++j) h[j] = T[k0+j][d];
    *(f16x8*)(vb + (size_t)n*8) = h;   // dense coalesced 16B chunks
  }
}

// ---- flash attention over one key-split ----
// grid (L/128, B, KSPLIT), block 256 = 4 waves; wave owns 32 q-rows (2 rowsets).
// BK=64 processed as two 32-key sub-tiles; lazy-rescale softmax (trigger+9);
// single-buffered K/V, 2 barriers per 64-key iter, staging drains 1 phase late.
__launch_bounds__(256, 2)
__global__ void flash_k(const _Float16* __restrict__ x16,
                        const _Float16* __restrict__ vtl,
                        const int* __restrict__ mask,
                        _Float16* __restrict__ oall,
                        float* __restrict__ mlm,
                        float* __restrict__ mll){
  __shared__ __attribute__((aligned(16))) _Float16 sK[64*256];   // 32 KB swizzled
  __shared__ __attribute__((aligned(16))) _Float16 sV[2*8192];   // 32 KB (2 tiles)
  __shared__ __attribute__((aligned(16))) _Float16 sP[4][1024];  // 8 KB (32x32 swz)

  const int tid  = threadIdx.x;
  const int wave = tid >> 6, lane = tid & 63;
  const int quad = lane >> 4, l16 = lane & 15;
  const int b = blockIdx.y, z = blockIdx.z;
  const int q0w = blockIdx.x*128 + wave*32;
  const int sw = l16 & 7, psw = l16 & 3, vsw = (l16>>1)&3;

  // ---- Q fragments: 2 rowsets x 8 k-steps ----
  f16x8 qh[2][8];
  #pragma unroll
  for (int rs=0; rs<2; ++rs){
    const _Float16* qr = x16 + ((size_t)(b*L_ + q0w + rs*16 + l16))*D_;
    #pragma unroll
    for (int ks=0; ks<8; ++ks)
      qh[rs][ks] = *(const f16x8*)(qr + ks*32 + quad*8);
  }

  // ---- mask bits: key j*16+l16 -> bit j ----
  unsigned mb = 0;
  {
    const int* mrow = mask + b*L_ + z*KQ;
    #pragma unroll
    for (int j=0;j<32;++j) mb |= (mrow[j*16 + l16] ? 1u : 0u) << j;
  }

  const char* kbase = (const char*)x16 + ((size_t)b*L_ + (size_t)z*KQ)*(D_*2);
  const char* vbase = (const char*)vtl + ((size_t)(b*64 + z*16))*16384;

  // ---- preload tile 0 ----
  #pragma unroll
  for (int i=0;i<8;++i){
    int s = wave + i*4;
    int r = s*2 + (lane>>5), lo = lane & 31;
    GLL(kbase + (unsigned)(r*512 + ((lo ^ (r&7))*16)), (char*)sK + s*1024);
    GLL(vbase + (unsigned)(s*1024 + lane*16),          (char*)sV + s*1024);
  }

  // ---- state ----
  f32x4 O[2][16], Osum[2], mref[2];
  #pragma unroll
  for (int rs=0; rs<2; ++rs){
    #pragma unroll
    for (int i=0;i<16;i++) O[rs][i] = (f32x4){0.f,0.f,0.f,0.f};
    Osum[rs] = (f32x4){0.f,0.f,0.f,0.f};
    mref[rs] = (f32x4){MREF0,MREF0,MREF0,MREF0};
  }
  f16x8 ones;
  #pragma unroll
  for (int j=0;j<8;++j) ones[j] = (_Float16)1.0f;

  __syncthreads();   // tile 0 visible

  for (int it=0; it<NIT; ++it){
    #pragma unroll
    for (int h=0; h<2; ++h){
      // ---- S = Q·K^T over 32-key sub-tile ----
      f32x4 S[2][2];
      S[0][0]=(f32x4){0,0,0,0}; S[0][1]=(f32x4){0,0,0,0};
      S[1][0]=(f32x4){0,0,0,0}; S[1][1]=(f32x4){0,0,0,0};
      #pragma unroll
      for (int ks=0; ks<8; ++ks){
        #pragma unroll
        for (int nt=0; nt<2; ++nt){
          const int n = h*32 + nt*16 + l16;
          f16x8 bk = *(const f16x8*)(sK + n*256 + (((ks*4+quad)^sw)*8));
          S[0][nt] = MFMA16F(qh[0][ks], bk, S[0][nt]);
          S[1][nt] = MFMA16F(qh[1][ks], bk, S[1][nt]);
        }
      }

      if (h==1){
        __syncthreads();   // B1: all sK reads of this iter done; V(it) long drained
        if (it+1 < NIT){   // stage K(it+1); drains at B2
          const char* kb = kbase + (size_t)(it+1)*32768;
          #pragma unroll
          for (int i=0;i<8;++i){
            int s = wave + i*4;
            int r = s*2 + (lane>>5), lo = lane & 31;
            GLL(kb + (unsigned)(r*512 + ((lo ^ (r&7))*16)), (char*)sK + s*1024);
          }
        }
      }

      // ---- diagonal zero (wave-uniform rare branch) ----
      #pragma unroll
      for (int rs=0; rs<2; ++rs){
        const int d0 = q0w + rs*16 - (z*KQ + it*64 + h*32);
        if ((unsigned)d0 < 32u){
          const int ntd = d0 >> 4;
          #pragma unroll
          for (int r=0;r<4;++r)
            S[rs][ntd][r] = (l16 == quad*4+r) ? 0.0f : S[rs][ntd][r];
        }
      }
      // ---- key padding mask ----
      #pragma unroll
      for (int nt=0; nt<2; ++nt){
        const float mk = ((mb >> (unsigned)(it*4 + h*2 + nt)) & 1u) ? NEG_INF : 0.0f;
        #pragma unroll
        for (int r=0;r<4;++r){ S[0][nt][r] += mk; S[1][nt][r] += mk; }
      }

      // ---- lazy softmax: trigger check, rare rescale ----
      f32x4 tmax0 = fmax4(S[0][0], S[0][1]);
      f32x4 tmax1 = fmax4(S[1][0], S[1][1]);
      bool trig = false;
      #pragma unroll
      for (int r=0;r<4;++r){
        trig = trig || (tmax0[r] > mref[0][r] + 9.0f) || (tmax1[r] > mref[1][r] + 9.0f);
      }
      if (__ballot(trig)){
        #pragma unroll
        for (int rs=0; rs<2; ++rs){
          f32x4 t = rs ? tmax1 : tmax0;
          #pragma unroll
          for (int off=1; off<16; off<<=1){
            f32x4 o;
            o[0]=__shfl_xor(t[0],off); o[1]=__shfl_xor(t[1],off);
            o[2]=__shfl_xor(t[2],off); o[3]=__shfl_xor(t[3],off);
            t = fmax4(t,o);
          }
          f32x4 mnew = fmax4(mref[rs], t);
          f32x4 alpha;
          #pragma unroll
          for (int r=0;r<4;++r) alpha[r] = __expf(mref[rs][r] - mnew[r]);
          #pragma unroll
          for (int vt=0; vt<16; ++vt) O[rs][vt] *= alpha;
          Osum[rs] *= alpha;
          mref[rs] = mnew;
        }
      }

      // ---- P = exp(S-mref) -> fp16 -> swizzled sP (wave-private) ----
      #pragma unroll
      for (int rs=0; rs<2; ++rs){
        #pragma unroll
        for (int r=0;r<4;++r){
          const int row = rs*16 + quad*4 + r;
          const int rsw = row & 3;
          _Float16* pb = &sP[wave][row*32 + (l16&7)];
          #pragma unroll
          for (int nt=0; nt<2; ++nt){
            float pv = __expf(S[rs][nt][r] - mref[rs][r]);
            pb[(((nt*2) + (l16>>3)) ^ rsw)*8] = (_Float16)pv;
          }
        }
      }
      __threadfence_block();
      f16x8 pf0 = *(const f16x8*)(&sP[wave][(     l16)*32 + ((quad^psw)*8)]);
      f16x8 pf1 = *(const f16x8*)(&sP[wave][(16 + l16)*32 + ((quad^psw)*8)]);

      // ---- O += P·V over this sub-tile ----
      const _Float16* vb = sV + h*8192;
      #pragma unroll
      for (int vt=0; vt<16; ++vt){
        f16x8 bv = *(const f16x8*)(vb + (vt*16+l16)*32 + ((quad^vsw)*8));
        O[0][vt] = MFMA16F(pf0, bv, O[0][vt]);
        O[1][vt] = MFMA16F(pf1, bv, O[1][vt]);
      }
      Osum[0] = MFMA16F(pf0, ones, Osum[0]);
      Osum[1] = MFMA16F(pf1, ones, Osum[1]);

      if (h==1){
        __syncthreads();   // B2: PV reads done; K(it+1) staging drained
        if (it+1 < NIT){   // stage V(it+1); drains at next B1
          const char* vv = vbase + (size_t)(it+1)*32768;
          #pragma unroll
          for (int i=0;i<8;++i){
            int s = wave + i*4;
            GLL(vv + (unsigned)(s*1024 + lane*16), (char*)sV + s*1024);
          }
        }
      }
    }
  }

  // ---- epilogue: fragment-major fp16 stores + (mref, l) ----
  #pragma unroll
  for (int rs=0; rs<2; ++rs){
    const int u = ((b*16 + blockIdx.x)*4 + wave)*2 + rs;
    _Float16* ob = oall + (size_t)z*NE + (size_t)u*4096;
    #pragma unroll
    for (int vt=0; vt<16; ++vt){
      hf4 hh;
      #pragma unroll
      for (int r=0;r<4;++r) hh[r] = (_Float16)O[rs][vt][r];
      *(hf4*)(ob + vt*256 + lane*4) = hh;
    }
    if (l16 == 0){
      #pragma unroll
      for (int r=0;r<4;++r){
        int row = u*16 + quad*4 + r;
        mlm[z*NROW + row] = mref[rs][r];
        mll[z*NROW + row] = Osum[rs][r];
      }
    }
  }
}

// ---- combine the key-splits: coalesced reads, LDS-staged coalesced writes ----
__global__ void combine_k(float* __restrict__ out,
                          const _Float16* __restrict__ oall,
                          const float* __restrict__ mlm,
                          const float* __restrict__ mll){
  __shared__ float T2[16][260];
  const int t = threadIdx.x, u = blockIdx.x;
  const int quad = (t>>4)&3, l16 = t&15;
  const int row0 = u*16 + quad*4;

  float4 mz[KSPLIT], lz[KSPLIT];
  float m[4] = {MREF0,MREF0,MREF0,MREF0};
  #pragma unroll
  for (int zc=0; zc<KSPLIT; ++zc){
    mz[zc] = *(const float4*)(mlm + zc*NROW + row0);
    lz[zc] = *(const float4*)(mll + zc*NROW + row0);
    m[0]=fmaxf(m[0],mz[zc].x); m[1]=fmaxf(m[1],mz[zc].y);
    m[2]=fmaxf(m[2],mz[zc].z); m[3]=fmaxf(m[3],mz[zc].w);
  }
  float w[KSPLIT][4], den[4]={0.f,0.f,0.f,0.f};
  #pragma unroll
  for (int zc=0; zc<KSPLIT; ++zc){
    const float* mzp = (const float*)&mz[zc];
    const float* lzp = (const float*)&lz[zc];
    #pragma unroll
    for (int r=0;r<4;++r){
      w[zc][r] = __expf(mzp[r] - m[r]);
      den[r] += lzp[r]*w[zc][r];
    }
  }
  #pragma unroll
  for (int r=0;r<4;++r){
    float inv = 1.0f/den[r];
    #pragma unroll
    for (int zc=0; zc<KSPLIT; ++zc) w[zc][r] *= inv;
  }
  #pragma unroll
  for (int i=0;i<4;++i){
    const int f = t + 256*i;
    const int vt = f>>6;
    float acc[4] = {0.f,0.f,0.f,0.f};
    #pragma unroll
    for (int zc=0; zc<KSPLIT; ++zc){
      hf4 v = *(const hf4*)(oall + (size_t)zc*NE + (size_t)u*4096 + (size_t)f*4);
      #pragma unroll
      for (int r=0;r<4;++r) acc[r] += w[zc][r]*(float)v[r];
    }
    #pragma unroll
    for (int r=0;r<4;++r) T2[quad*4+r][vt*16+l16] = acc[r];
  }
  __syncthreads();
  #pragma unroll
  for (int p=0;p<4;++p){
    const int row = (t>>6) + p*4, col = (t&63)*4;
    float4 vv = *(const float4*)&T2[row][col];
    *(float4*)(out + ((size_t)u*16 + row)*D_ + col) = vv;
  }
}

extern "C" void kernel_launch(void* const* d_in, const int* in_sizes, int n_in,
                              void* d_out, int out_size, void* d_ws, size_t ws_size,
                              hipStream_t stream) {
  const float* x    = (const float*)d_in[0];
  const int*   mask = (const int*)d_in[1];
  float*       out  = (float*)d_out;

  _Float16* x16  = (_Float16*)d_ws;
  _Float16* vtl  = x16 + NE;
  _Float16* oall = vtl + NE;                       // KSPLIT*NE fp16
  float*    mlm  = (float*)(oall + (size_t)KSPLIT*NE);
  float*    mll  = mlm + (size_t)KSPLIT*NROW;      // total ~51 MB

  prep_k   <<<dim3(L_/64, B_), dim3(256), 0, stream>>>(x, x16, vtl);
  flash_k  <<<dim3(L_/128, B_, KSPLIT), dim3(256), 0, stream>>>(x16, vtl, mask, oall, mlm, mll);
  combine_k<<<dim3(NROW/16), dim3(256), 0, stream>>>(out, oall, mlm, mll);
}